// Round 3
// baseline (799.976 us; speedup 1.0000x reference)
//
#include <hip/hip_runtime.h>

// MLMM electrostatics: per-pair energy -> scatter-add onto ML atoms.
//  0 atomic_charges      [NML]        f32
//  1 mm_atomic_charges   [NMM]        f32
//  2 atomic_dipoles      [NML,3]      f32
//  3 atomic_quadrupoles  [NML,3,3]    f32
//  4 atomic_energies     [NML]        f32
//  5 mlmm_distances_uv   [P]          f32
//  6 mlmm_vectors_uv     [P,3]        f32
//  7 mlmm_outer_product_uv [P,3,3]    f32
//  8 mlmm_idx_u          [P]          i32
//  9 mlmm_idx_v          [P]          i32
// out: atomic_energies + segment_sum(Eelec, idx_u)   [NML] f32
//
// R1 finding: atomicAdd(float*) emits a CAS retry loop on gfx950 (safe-fp-
// atomics default) -> 7M serialized RMW chains, 205MB write-through, 395us
// (VALUBusy 2.9%, HBM 20%) — latency-bound on the atomic path.
// R2 fix: unsafeAtomicAdd -> native global_atomic_add_f32 (fire-and-forget).
// NT loads for the 480MB pair stream so 3.4MB gather tables stay cache-resident.
// R2 compile fix: __builtin_nontemporal_load needs clang ext_vector_type,
// not HIP_vector_type structs.

static constexpr float KE_F     = 14.399645351950548f;
static constexpr float CUTOFF_F = 10.0f;

typedef float cf4 __attribute__((ext_vector_type(4)));
typedef int   ci4 __attribute__((ext_vector_type(4)));

__global__ void init_out_kernel(const float* __restrict__ energies,
                                float* __restrict__ out, int n) {
    int i = blockIdx.x * blockDim.x + threadIdx.x;
    if (i < n) out[i] = energies[i];
}

__device__ __forceinline__ void pair_contrib(
    float di, int ui, int vi,
    const float* __restrict__ vp,   // 3 floats: pair vector
    const float* __restrict__ op,   // 9 floats: pair outer product
    const float* __restrict__ q_ml,
    const float* __restrict__ q_mm,
    const float* __restrict__ mu,   // [NML,3]
    const float* __restrict__ Q,    // [NML,9]
    float* __restrict__ out)
{
    if (di > CUTOFF_F) return;          // masked pair: no table load, no atomic
    float chi  = 1.0f / di;
    float chi2 = chi * chi;
    float chi3 = chi2 * chi;
    float chi5 = chi3 * chi2;

    float qu = q_ml[ui];
    float qv = q_mm[vi];

    const float* m = mu + 3 * ui;
    float dot = vp[0]*m[0] + vp[1]*m[1] + vp[2]*m[2];

    const float* qq = Q + 9 * ui;
    float S = op[0]*qq[0] + op[1]*qq[1] + op[2]*qq[2]
            + op[3]*qq[3] + op[4]*qq[4] + op[5]*qq[5]
            + op[6]*qq[6] + op[7]*qq[7] + op[8]*qq[8];
    float dm  = (op[0] + op[4] + op[8]) * (1.0f / 3.0f);
    float trQ = qq[0] + qq[4] + qq[8];

    // E = KE * q_v * ( q_u*chi - chi3*(vec.mu) + chi5*(S - dm*trQ) )
    float E = KE_F * qv * (qu * chi - chi3 * dot + chi5 * (S - dm * trQ));
    // Native HW f32 atomic (global_atomic_add_f32, no return) — NOT the CAS loop.
    unsafeAtomicAdd(out + ui, E);
}

__global__ __launch_bounds__(256) void mlmm_pair_kernel(
    const float* __restrict__ q_ml,
    const float* __restrict__ q_mm,
    const float* __restrict__ mu,
    const float* __restrict__ Q,
    const float* __restrict__ dist,
    const float* __restrict__ vec,
    const float* __restrict__ outer,
    const int*   __restrict__ idx_u,
    const int*   __restrict__ idx_v,
    float* __restrict__ out,
    int n4, int npairs)
{
    int t = blockIdx.x * blockDim.x + threadIdx.x;

    if (t < n4) {
        // ---- fully aligned 16B non-temporal staging of 4 consecutive pairs ----
        const cf4* d4  = (const cf4*)dist;   // 1 x 16B
        const ci4* iu4 = (const ci4*)idx_u;  // 1 x 16B
        const ci4* iv4 = (const ci4*)idx_v;  // 1 x 16B
        const cf4* v4  = (const cf4*)vec;    // 3 x 16B (12 floats)
        const cf4* o4  = (const cf4*)outer;  // 9 x 16B (36 floats, 144B)

        cf4 d = __builtin_nontemporal_load(d4 + t);
        ci4 u = __builtin_nontemporal_load(iu4 + t);
        ci4 v = __builtin_nontemporal_load(iv4 + t);

        cf4 vv[3];
        #pragma unroll
        for (int k = 0; k < 3; ++k) vv[k] = __builtin_nontemporal_load(v4 + 3 * t + k);
        cf4 oo[9];
        #pragma unroll
        for (int k = 0; k < 9; ++k) oo[k] = __builtin_nontemporal_load(o4 + 9 * t + k);

        const float* vf = (const float*)vv;  // 12 floats = 4 pairs x 3
        const float* of = (const float*)oo;  // 36 floats = 4 pairs x 9
        float dd[4] = {d.x, d.y, d.z, d.w};
        int   uu[4] = {u.x, u.y, u.z, u.w};
        int   wv[4] = {v.x, v.y, v.z, v.w};

        #pragma unroll
        for (int p = 0; p < 4; ++p) {
            pair_contrib(dd[p], uu[p], wv[p], vf + 3 * p, of + 9 * p,
                         q_ml, q_mm, mu, Q, out);
        }
    }

    // ---- tail (P not multiple of 4): first threads of block 0 ----
    int tail = npairs - 4 * n4;
    if (blockIdx.x == 0 && (int)threadIdx.x < tail) {
        int i = 4 * n4 + threadIdx.x;
        pair_contrib(dist[i], idx_u[i], idx_v[i],
                     vec + 3 * i, outer + 9 * i,
                     q_ml, q_mm, mu, Q, out);
    }
}

extern "C" void kernel_launch(void* const* d_in, const int* in_sizes, int n_in,
                              void* d_out, int out_size, void* d_ws, size_t ws_size,
                              hipStream_t stream) {
    const float* q_ml   = (const float*)d_in[0];
    const float* q_mm   = (const float*)d_in[1];
    const float* mu     = (const float*)d_in[2];
    const float* Q      = (const float*)d_in[3];
    const float* ene    = (const float*)d_in[4];
    const float* dist   = (const float*)d_in[5];
    const float* vec    = (const float*)d_in[6];
    const float* outer  = (const float*)d_in[7];
    const int*   idx_u  = (const int*)d_in[8];
    const int*   idx_v  = (const int*)d_in[9];
    float* out = (float*)d_out;

    int nml    = in_sizes[4];   // NML
    int npairs = in_sizes[5];   // P
    int n4     = npairs >> 2;

    // 1) out = atomic_energies  (d_out is re-poisoned before every call)
    {
        int threads = 256;
        int blocks = (nml + threads - 1) / threads;
        init_out_kernel<<<blocks, threads, 0, stream>>>(ene, out, nml);
    }
    // 2) pair energies + scatter atomics (same stream -> ordered after init)
    {
        int threads = 256;
        int blocks = (n4 + threads - 1) / threads;
        if (blocks < 1) blocks = 1;
        mlmm_pair_kernel<<<blocks, threads, 0, stream>>>(
            q_ml, q_mm, mu, Q, dist, vec, outer, idx_u, idx_v, out, n4, npairs);
    }
}

// Round 4
// 718.663 us; speedup vs baseline: 1.1131x; 1.1131x over previous
//
#include <hip/hip_runtime.h>

// MLMM electrostatics.
// R1/R3 finding: 6.6M device-scope f32 atomics hit a fabric atomic-rate limit
// (~16/ns chip-wide): WRITE_SIZE 205MB (32B/atomic), VALUBusy 2.9%, HBM 18%,
// 400us regardless of CAS-loop vs native global_atomic_add_f32.
// R4: eliminate global atomics entirely — 3-phase privatized segment-sum:
//   P1: stream pairs -> masked per-pair E into ws          (480MB rd, 32MB wr)
//   P2: 4 subset-groups x 128 blocks, 50KB LDS private acc (L3-resident rd)
//   P3: out[u] = energies[u] + sum_b partial[b][u]         (26MB rd, no atomics)

static constexpr float KE_F     = 14.399645351950548f;
static constexpr float CUTOFF_F = 10.0f;

typedef float cf4 __attribute__((ext_vector_type(4)));
typedef int   ci4 __attribute__((ext_vector_type(4)));

#define BPG        128    // blocks per subset-group (phase 2)
#define SUBSETS    4
#define MAX_SUBN   12544  // floats of LDS accumulator (50176 B)
#define P2_THREADS 1024

// ---------------- shared pair math ----------------
__device__ __forceinline__ float pair_energy(
    float di, int ui, int vi,
    const float* __restrict__ vp,   // 3 floats
    const float* __restrict__ op,   // 9 floats
    const float* __restrict__ q_ml,
    const float* __restrict__ q_mm,
    const float* __restrict__ mu,
    const float* __restrict__ Q)
{
    if (di > CUTOFF_F) return 0.0f;
    float chi  = 1.0f / di;
    float chi2 = chi * chi;
    float chi3 = chi2 * chi;
    float chi5 = chi3 * chi2;

    float qu = q_ml[ui];
    float qv = q_mm[vi];

    const float* m = mu + 3 * ui;
    float dot = vp[0]*m[0] + vp[1]*m[1] + vp[2]*m[2];

    const float* qq = Q + 9 * ui;
    float S = op[0]*qq[0] + op[1]*qq[1] + op[2]*qq[2]
            + op[3]*qq[3] + op[4]*qq[4] + op[5]*qq[5]
            + op[6]*qq[6] + op[7]*qq[7] + op[8]*qq[8];
    float dm  = (op[0] + op[4] + op[8]) * (1.0f / 3.0f);
    float trQ = qq[0] + qq[4] + qq[8];

    return KE_F * qv * (qu * chi - chi3 * dot + chi5 * (S - dm * trQ));
}

// ---------------- Phase 1: per-pair E -> ws (no atomics) ----------------
__global__ __launch_bounds__(256) void pair_energy_kernel(
    const float* __restrict__ q_ml,
    const float* __restrict__ q_mm,
    const float* __restrict__ mu,
    const float* __restrict__ Q,
    const float* __restrict__ dist,
    const float* __restrict__ vec,
    const float* __restrict__ outer,
    const int*   __restrict__ idx_u,
    const int*   __restrict__ idx_v,
    float* __restrict__ E_out,
    int n4, int npairs)
{
    int t = blockIdx.x * blockDim.x + threadIdx.x;

    if (t < n4) {
        const cf4* d4  = (const cf4*)dist;
        const ci4* iu4 = (const ci4*)idx_u;
        const ci4* iv4 = (const ci4*)idx_v;
        const cf4* v4  = (const cf4*)vec;
        const cf4* o4  = (const cf4*)outer;

        cf4 d = __builtin_nontemporal_load(d4 + t);
        ci4 u = iu4[t];                         // idx_u reused by phase 2 -> cacheable
        ci4 v = __builtin_nontemporal_load(iv4 + t);

        cf4 vv[3];
        #pragma unroll
        for (int k = 0; k < 3; ++k) vv[k] = __builtin_nontemporal_load(v4 + 3 * t + k);
        cf4 oo[9];
        #pragma unroll
        for (int k = 0; k < 9; ++k) oo[k] = __builtin_nontemporal_load(o4 + 9 * t + k);

        const float* vf = (const float*)vv;
        const float* of = (const float*)oo;
        float dd[4] = {d.x, d.y, d.z, d.w};
        int   uu[4] = {u.x, u.y, u.z, u.w};
        int   wv[4] = {v.x, v.y, v.z, v.w};

        cf4 e;
        #pragma unroll
        for (int p = 0; p < 4; ++p) {
            float ev = pair_energy(dd[p], uu[p], wv[p], vf + 3*p, of + 9*p,
                                   q_ml, q_mm, mu, Q);
            ((float*)&e)[p] = ev;
        }
        ((cf4*)E_out)[t] = e;                   // cacheable: phase 2 reads it (L3)
    }

    int tail = npairs - 4 * n4;
    if (blockIdx.x == 0 && (int)threadIdx.x < tail) {
        int i = 4 * n4 + threadIdx.x;
        E_out[i] = pair_energy(dist[i], idx_u[i], idx_v[i],
                               vec + 3*i, outer + 9*i, q_ml, q_mm, mu, Q);
    }
}

// ---------------- Phase 2: LDS-privatized segment sum ----------------
__global__ __launch_bounds__(P2_THREADS) void segsum_lds_kernel(
    const int*   __restrict__ idx_u,
    const float* __restrict__ E,
    float* __restrict__ partial,     // [SUBSETS*BPG][subn]
    int n4, int npairs, int subn, int nml)
{
    __shared__ float sacc[MAX_SUBN];

    int s  = blockIdx.x >> 7;        // / BPG
    int b  = blockIdx.x & (BPG - 1);
    int lo = s * subn;
    int hi = lo + subn; if (hi > nml) hi = nml;

    for (int j = threadIdx.x; j < subn; j += P2_THREADS) sacc[j] = 0.0f;
    __syncthreads();

    const ci4* iu4 = (const ci4*)idx_u;
    const cf4* e4  = (const cf4*)E;

    for (int t = b * P2_THREADS + threadIdx.x; t < n4; t += BPG * P2_THREADS) {
        ci4 u = iu4[t];
        cf4 e = e4[t];
        if (e.x != 0.0f && u.x >= lo && u.x < hi) atomicAdd(&sacc[u.x - lo], e.x);
        if (e.y != 0.0f && u.y >= lo && u.y < hi) atomicAdd(&sacc[u.y - lo], e.y);
        if (e.z != 0.0f && u.z >= lo && u.z < hi) atomicAdd(&sacc[u.z - lo], e.z);
        if (e.w != 0.0f && u.w >= lo && u.w < hi) atomicAdd(&sacc[u.w - lo], e.w);
    }

    int tail = npairs - 4 * n4;
    if (b == 0 && (int)threadIdx.x < tail) {
        int i  = 4 * n4 + threadIdx.x;
        int ui = idx_u[i];
        float ev = E[i];
        if (ev != 0.0f && ui >= lo && ui < hi) atomicAdd(&sacc[ui - lo], ev);
    }

    __syncthreads();
    float* dst = partial + (size_t)blockIdx.x * subn;
    for (int j = threadIdx.x; j < subn; j += P2_THREADS) dst[j] = sacc[j];
}

// ---------------- Phase 3: reduce partials, add energies ----------------
__global__ __launch_bounds__(256) void reduce_partials_kernel(
    const float* __restrict__ energies,
    const float* __restrict__ partial,
    float* __restrict__ out,
    int nml, int subn)
{
    int u = blockIdx.x * 256 + threadIdx.x;
    if (u >= nml) return;
    int s = u / subn;
    int j = u - s * subn;
    const float* p = partial + (size_t)(s * BPG) * subn + j;
    float acc = energies[u];
    #pragma unroll 4
    for (int b = 0; b < BPG; ++b) acc += p[(size_t)b * subn];
    out[u] = acc;
}

// ---------------- Fallback (ws too small): R3 atomic path ----------------
__global__ void init_out_kernel(const float* __restrict__ energies,
                                float* __restrict__ out, int n) {
    int i = blockIdx.x * blockDim.x + threadIdx.x;
    if (i < n) out[i] = energies[i];
}

__global__ __launch_bounds__(256) void mlmm_pair_atomic_kernel(
    const float* __restrict__ q_ml, const float* __restrict__ q_mm,
    const float* __restrict__ mu,   const float* __restrict__ Q,
    const float* __restrict__ dist, const float* __restrict__ vec,
    const float* __restrict__ outer,
    const int* __restrict__ idx_u,  const int* __restrict__ idx_v,
    float* __restrict__ out, int npairs)
{
    int i = blockIdx.x * blockDim.x + threadIdx.x;
    if (i >= npairs) return;
    float ev = pair_energy(dist[i], idx_u[i], idx_v[i],
                           vec + 3*i, outer + 9*i, q_ml, q_mm, mu, Q);
    if (ev != 0.0f) unsafeAtomicAdd(out + idx_u[i], ev);
}

extern "C" void kernel_launch(void* const* d_in, const int* in_sizes, int n_in,
                              void* d_out, int out_size, void* d_ws, size_t ws_size,
                              hipStream_t stream) {
    const float* q_ml   = (const float*)d_in[0];
    const float* q_mm   = (const float*)d_in[1];
    const float* mu     = (const float*)d_in[2];
    const float* Q      = (const float*)d_in[3];
    const float* ene    = (const float*)d_in[4];
    const float* dist   = (const float*)d_in[5];
    const float* vec    = (const float*)d_in[6];
    const float* outer  = (const float*)d_in[7];
    const int*   idx_u  = (const int*)d_in[8];
    const int*   idx_v  = (const int*)d_in[9];
    float* out = (float*)d_out;

    int nml    = in_sizes[4];
    int npairs = in_sizes[5];
    int n4     = npairs >> 2;
    int subn   = (nml + SUBSETS - 1) / SUBSETS;

    size_t e_bytes   = (size_t)npairs * sizeof(float);
    size_t e_aligned = (e_bytes + 255) & ~(size_t)255;
    size_t p_bytes   = (size_t)SUBSETS * BPG * subn * sizeof(float);
    bool   use_fast  = (subn <= MAX_SUBN) && (ws_size >= e_aligned + p_bytes);

    if (use_fast) {
        float* ws_E = (float*)d_ws;
        float* ws_P = (float*)((char*)d_ws + e_aligned);

        {
            int blocks = (n4 + 255) / 256;
            if (blocks < 1) blocks = 1;
            pair_energy_kernel<<<blocks, 256, 0, stream>>>(
                q_ml, q_mm, mu, Q, dist, vec, outer, idx_u, idx_v,
                ws_E, n4, npairs);
        }
        segsum_lds_kernel<<<SUBSETS * BPG, P2_THREADS, 0, stream>>>(
            idx_u, ws_E, ws_P, n4, npairs, subn, nml);
        {
            int blocks = (nml + 255) / 256;
            reduce_partials_kernel<<<blocks, 256, 0, stream>>>(
                ene, ws_P, out, nml, subn);
        }
    } else {
        int threads = 256;
        init_out_kernel<<<(nml + threads - 1) / threads, threads, 0, stream>>>(ene, out, nml);
        mlmm_pair_atomic_kernel<<<(npairs + threads - 1) / threads, threads, 0, stream>>>(
            q_ml, q_mm, mu, Q, dist, vec, outer, idx_u, idx_v, out, npairs);
    }
}